// Round 8
// baseline (323.044 us; speedup 1.0000x reference)
//
#include <hip/hip_runtime.h>
#include <hip/hip_bf16.h>

// Problem constants
#define BB 32
#define QQ 300
#define DD 256
#define HH 8
#define DHH 32
#define LL 4
#define PP 4
#define SS 8500

typedef __attribute__((ext_vector_type(8))) short bf16x8;
typedef __attribute__((ext_vector_type(4))) float f32x4;

__device__ inline unsigned short f2bf(float f) {
  unsigned int u = __builtin_bit_cast(unsigned int, f);
  unsigned int r = (u + 0x7FFFu + ((u >> 16) & 1u)) >> 16;
  return (unsigned short)r;
}

// ---------------------------------------------------------------------------
// Convert W_val (256x256 f32, [k][n]) -> bf16 [n][k] with T2 XOR swizzle
// (k ^= (n&7)<<3; mask < 64 so each 64-aligned k-window is self-contained).
// ---------------------------------------------------------------------------
__global__ __launch_bounds__(256) void wcvt_kernel(const float* __restrict__ W,
                                                   unsigned short* __restrict__ wbfS) {
  int t = blockIdx.x * 256 + threadIdx.x;   // 0..65535
  int k = t >> 8, n = t & 255;              // coalesced read of W[k][*]
  wbfS[n * 256 + (k ^ ((n & 7) << 3))] = f2bf(W[(size_t)k * 256 + n]);
}

// ---------------------------------------------------------------------------
// Value GEMM: C[M x 256] = bf16(A[M x 256] f32) @ bf16(W) + bias.
// 256 threads = 4 waves; BM=64 (wave owns 16 rows x all 256 cols -> A read
// once). B staged async via global_load_lds (pre-swizzled source). A staged
// with the same XOR swizzle (no pad) -> LDS = 40 KB exactly -> 4 blocks/CU.
// ---------------------------------------------------------------------------
__global__ __launch_bounds__(256, 4) void gemm_val_mfma(
    const float* __restrict__ A, const unsigned short* __restrict__ WbfS,
    const float* __restrict__ bias, __hip_bfloat16* __restrict__ C) {
  __shared__ __align__(16) unsigned short Alds[64 * 64];  // 8 KB, swizzled
  __shared__ __align__(16) unsigned short Blds[256 * 64]; // 32 KB, swizzled

  const int t = threadIdx.x;
  const int lane = t & 63;
  const int w = t >> 6;            // wave 0..3 -> rows w*16..w*16+15
  const int lm = lane & 15, lg = lane >> 4;
  const int row0 = blockIdx.x * 64;

  f32x4 acc[16];
#pragma unroll
  for (int nf = 0; nf < 16; ++nf) acc[nf] = {0.f, 0.f, 0.f, 0.f};

  for (int k0 = 0; k0 < 256; k0 += 64) {
    // --- B: 8 async global_load_lds (16 B) per wave, zero VGPR ---
#pragma unroll
    for (int i = 0; i < 8; ++i) {
      const unsigned short* gp = WbfS +
          (size_t)(w * 64 + i * 8 + (lane >> 3)) * 256 + k0 + (lane & 7) * 8;
      unsigned char* lp = reinterpret_cast<unsigned char*>(Blds) + (w * 8 + i) * 1024;
      __builtin_amdgcn_global_load_lds(
          (const __attribute__((address_space(1))) void*)gp,
          (__attribute__((address_space(3))) void*)lp, 16, 0, 0);
    }
    // --- A: 64 rows x 64 f32 -> bf16 into Alds (XOR-swizzled store) ---
#pragma unroll
    for (int i = 0; i < 4; ++i) {
      int u = i * 256 + t;
      int r = u >> 4, c4 = (u & 15) * 4;
      float4 v = *reinterpret_cast<const float4*>(A + (size_t)(row0 + r) * 256 + k0 + c4);
      ushort4 h;
      h.x = f2bf(v.x); h.y = f2bf(v.y); h.z = f2bf(v.z); h.w = f2bf(v.w);
      *reinterpret_cast<ushort4*>(&Alds[r * 64 + (c4 ^ ((r & 7) << 3))]) = h;
    }
    __syncthreads();

    // --- compute: 2 ks x 16 nf MFMA per wave ---
#pragma unroll
    for (int ks = 0; ks < 2; ++ks) {
      const int kk = (ks * 32 + lg * 8) ^ ((lm & 7) << 3);   // un-swizzle
      const bf16x8 af = *reinterpret_cast<const bf16x8*>(&Alds[(w * 16 + lm) * 64 + kk]);
#pragma unroll
      for (int nf = 0; nf < 16; ++nf) {
        const bf16x8 bfr = *reinterpret_cast<const bf16x8*>(&Blds[(nf * 16 + lm) * 64 + kk]);
        acc[nf] = __builtin_amdgcn_mfma_f32_16x16x32_bf16(af, bfr, acc[nf], 0, 0, 0);
      }
    }
    __syncthreads();
  }

  // Epilogue: C/D layout col=lane&15, row=(lane>>4)*4+j
  const int rb = row0 + w * 16 + lg * 4;
#pragma unroll
  for (int nf = 0; nf < 16; ++nf) {
    const int col = nf * 16 + lm;
    const float bv = bias[col];
#pragma unroll
    for (int j = 0; j < 4; ++j)
      C[(size_t)(rb + j) * 256 + col] = __float2bfloat16(acc[nf][j] + bv);
  }
}

// ---------------------------------------------------------------------------
// Fused per-query pipeline: off-proj + attn-proj + softmax + bilinear
// sampling + out-proj. Block = 8 queries x 32 threads. fp32 GEMM parts
// (positions must stay fp32); W matrices streamed from L2 via float4.
// ---------------------------------------------------------------------------
#define QPB 8

__global__ __launch_bounds__(256) void fused_query_kernel(
    const float* __restrict__ hidden, const __hip_bfloat16* __restrict__ value,
    const float* __restrict__ refpts,
    const float* __restrict__ W_off, const float* __restrict__ b_off,
    const float* __restrict__ W_attn, const float* __restrict__ b_attn,
    const float* __restrict__ W_out, const float* __restrict__ b_out,
    float* __restrict__ out) {
  __shared__ float s_hid[QPB][256];
  __shared__ float s_off[QPB][256];
  __shared__ float s_lg[QPB][128];
  __shared__ float s_samp[QPB][256];
  __shared__ float s_ref[QPB][4];

  const int nb = gridDim.x;   // 1200, divisible by 8
  const int bswz = (blockIdx.x % 8) * (nb / 8) + blockIdx.x / 8;
  const int bq0 = bswz * QPB;
  const int t = threadIdx.x;
  const int q = t >> 5;        // query in block
  const int sub = t & 31;

  // Phase 0: stage hidden rows + refpts
#pragma unroll
  for (int i = 0; i < QPB; ++i) {
    int idx = i * 256 + t;
    s_hid[idx >> 8][idx & 255] = hidden[(size_t)bq0 * 256 + idx];
  }
  if (t < QPB * 4) s_ref[t >> 2][t & 3] = refpts[(size_t)bq0 * 4 + t];
  __syncthreads();

  // Phase 1: off (8 cols/thread) + logits (4 cols/thread), fp32
  {
    float accO[8], accL[4];
#pragma unroll
    for (int c = 0; c < 8; ++c) accO[c] = b_off[sub * 8 + c];
#pragma unroll
    for (int c = 0; c < 4; ++c) accL[c] = b_attn[sub * 4 + c];
    for (int k = 0; k < 256; k += 4) {
      const float4 hv = *reinterpret_cast<const float4*>(&s_hid[q][k]);
      const float hh[4] = {hv.x, hv.y, hv.z, hv.w};
#pragma unroll
      for (int u = 0; u < 4; ++u) {
        const float4 w0 = *reinterpret_cast<const float4*>(W_off + (size_t)(k + u) * 256 + sub * 8);
        const float4 w1 = *reinterpret_cast<const float4*>(W_off + (size_t)(k + u) * 256 + sub * 8 + 4);
        const float4 wa = *reinterpret_cast<const float4*>(W_attn + (size_t)(k + u) * 128 + sub * 4);
        accO[0] += hh[u] * w0.x; accO[1] += hh[u] * w0.y;
        accO[2] += hh[u] * w0.z; accO[3] += hh[u] * w0.w;
        accO[4] += hh[u] * w1.x; accO[5] += hh[u] * w1.y;
        accO[6] += hh[u] * w1.z; accO[7] += hh[u] * w1.w;
        accL[0] += hh[u] * wa.x; accL[1] += hh[u] * wa.y;
        accL[2] += hh[u] * wa.z; accL[3] += hh[u] * wa.w;
      }
    }
#pragma unroll
    for (int c = 0; c < 8; ++c) s_off[q][sub * 8 + c] = accO[c];
#pragma unroll
    for (int c = 0; c < 4; ++c) s_lg[q][sub * 4 + c] = accL[c];
  }
  __syncthreads();

  // Phase 2: softmax (per-head, redundant x4) + bilinear sampling
  {
    const int h = sub >> 2;     // head
    const int c4 = sub & 3;     // channel group (8 ch)
    const int bq = bq0 + q;
    const int b = bq / QQ;

    float w[16];
    {
      const float* lg = &s_lg[q][h * 16];
      float m = lg[0];
#pragma unroll
      for (int j = 1; j < 16; ++j) m = fmaxf(m, lg[j]);
      float s = 0.f;
#pragma unroll
      for (int j = 0; j < 16; ++j) { w[j] = __expf(lg[j] - m); s += w[j]; }
      float inv = 1.f / s;
#pragma unroll
      for (int j = 0; j < 16; ++j) w[j] *= inv;
    }

    const float rx = s_ref[q][0], ry = s_ref[q][1];
    const float rw = s_ref[q][2], rh = s_ref[q][3];
    const unsigned short* vb =
        (const unsigned short*)value + (size_t)b * SS * DD + h * DHH + c4 * 8;

    float acc[8];
#pragma unroll
    for (int j = 0; j < 8; ++j) acc[j] = 0.f;

    const int dims[4] = {80, 40, 20, 10};
    const int sts[4] = {0, 6400, 8000, 8400};

#pragma unroll
    for (int l = 0; l < LL; ++l) {
      const int dim = dims[l];
      const int st = sts[l];
      const float fdim = (float)dim;
#pragma unroll
      for (int p = 0; p < PP; ++p) {
        const int tapi = l * 4 + p;
        const int oi = (h * 16 + tapi) * 2;
        const float locx = rx + s_off[q][oi] * rw * 0.125f;
        const float locy = ry + s_off[q][oi + 1] * rh * 0.125f;
        const float x = locx * fdim - 0.5f;
        const float y = locy * fdim - 0.5f;
        const float x0f = floorf(x), y0f = floorf(y);
        const float fx = x - x0f, fy = y - y0f;
        const int x0 = (int)x0f, y0 = (int)y0f;
        const float wt = w[tapi];
        const float bw[4] = {(1.f - fx) * (1.f - fy), fx * (1.f - fy),
                             (1.f - fx) * fy, fx * fy};
        const int cx[4] = {x0, x0 + 1, x0, x0 + 1};
        const int cy[4] = {y0, y0, y0 + 1, y0 + 1};
#pragma unroll
        for (int c = 0; c < 4; ++c) {
          const int xi = cx[c], yi = cy[c];
          const bool valid = (xi >= 0) & (xi < dim) & (yi >= 0) & (yi < dim);
          const int xc = min(max(xi, 0), dim - 1);
          const int yc = min(max(yi, 0), dim - 1);
          const uint4 v = *reinterpret_cast<const uint4*>(
              vb + (size_t)(st + yc * dim + xc) * DD);
          const float wv = valid ? bw[c] * wt : 0.f;
          const unsigned u[4] = {v.x, v.y, v.z, v.w};
#pragma unroll
          for (int k = 0; k < 4; ++k) {
            const float lo = __builtin_bit_cast(float, u[k] << 16);
            const float hi = __builtin_bit_cast(float, u[k] & 0xFFFF0000u);
            acc[2 * k] += lo * wv;
            acc[2 * k + 1] += hi * wv;
          }
        }
      }
    }
#pragma unroll
    for (int j = 0; j < 8; ++j) s_samp[q][h * DHH + c4 * 8 + j] = acc[j];
  }
  __syncthreads();

  // Phase 3: out = samp @ W_out + b_out (8 cols/thread, fp32)
  {
    float accU[8];
#pragma unroll
    for (int c = 0; c < 8; ++c) accU[c] = b_out[sub * 8 + c];
    for (int k = 0; k < 256; k += 4) {
      const float4 sv = *reinterpret_cast<const float4*>(&s_samp[q][k]);
      const float hh[4] = {sv.x, sv.y, sv.z, sv.w};
#pragma unroll
      for (int u = 0; u < 4; ++u) {
        const float4 w0 = *reinterpret_cast<const float4*>(W_out + (size_t)(k + u) * 256 + sub * 8);
        const float4 w1 = *reinterpret_cast<const float4*>(W_out + (size_t)(k + u) * 256 + sub * 8 + 4);
        accU[0] += hh[u] * w0.x; accU[1] += hh[u] * w0.y;
        accU[2] += hh[u] * w0.z; accU[3] += hh[u] * w0.w;
        accU[4] += hh[u] * w1.x; accU[5] += hh[u] * w1.y;
        accU[6] += hh[u] * w1.z; accU[7] += hh[u] * w1.w;
      }
    }
    float* outp = out + (size_t)(bq0 + q) * 256 + sub * 8;
    *reinterpret_cast<float4*>(outp) = make_float4(accU[0], accU[1], accU[2], accU[3]);
    *reinterpret_cast<float4*>(outp + 4) = make_float4(accU[4], accU[5], accU[6], accU[7]);
  }
}

// ---------------------------------------------------------------------------
// Launch
// ---------------------------------------------------------------------------
extern "C" void kernel_launch(void* const* d_in, const int* in_sizes, int n_in,
                              void* d_out, int out_size, void* d_ws, size_t ws_size,
                              hipStream_t stream) {
  const float* hidden = (const float*)d_in[0];
  const float* ehs    = (const float*)d_in[1];
  const float* refpts = (const float*)d_in[2];
  const float* W_val  = (const float*)d_in[3];
  const float* b_val  = (const float*)d_in[4];
  const float* W_off  = (const float*)d_in[5];
  const float* b_off  = (const float*)d_in[6];
  const float* W_attn = (const float*)d_in[7];
  const float* b_attn = (const float*)d_in[8];
  const float* W_out  = (const float*)d_in[9];
  const float* b_out  = (const float*)d_in[10];
  float* out = (float*)d_out;

  // Workspace layout
  char* ws = (char*)d_ws;
  __hip_bfloat16* value = (__hip_bfloat16*)ws;                 // 139,264,000 B
  unsigned short* wbfS = (unsigned short*)(ws + 139264000);    // 131,072 B

  const int M_val = BB * SS;   // 272000
  const int M_q   = BB * QQ;   // 9600

  // 0. W_val -> bf16 [n][k], XOR-swizzled
  wcvt_kernel<<<256, 256, 0, stream>>>(W_val, wbfS);
  // 1. value = ehs @ W_val + b_val  (bf16 MFMA)
  gemm_val_mfma<<<M_val / 64, 256, 0, stream>>>(ehs, wbfS, b_val, value);
  // 2. fused: off/attn projections + softmax + sampling + out projection
  fused_query_kernel<<<M_q / QPB, 256, 0, stream>>>(
      hidden, value, refpts, W_off, b_off, W_attn, b_attn, W_out, b_out, out);
}